// Round 8
// baseline (259.852 us; speedup 1.0000x reference)
//
#include <hip/hip_runtime.h>
#include <math.h>

// Problem constants (fixed by reference)
constexpr int Bc = 2, Sc = 2048, Dc = 512, Hc = 8, DHc = 64;
constexpr int NQKV = 3 * Dc;  // 1536

typedef unsigned short u16;
typedef unsigned int u32;
typedef __attribute__((ext_vector_type(8))) __bf16 bf16x8;
typedef __attribute__((ext_vector_type(16))) float f32x16;

#define MFMA32 __builtin_amdgcn_mfma_f32_32x32x16_bf16

// Direct HBM -> LDS (16B per lane, wave-uniform LDS base + lane*16).
__device__ __forceinline__ void gload16(const u16* g, u16* l) {
  __builtin_amdgcn_global_load_lds(
      (const __attribute__((address_space(1))) void*)g,
      (__attribute__((address_space(3))) void*)l, 16, 0, 0);
}

// Truncation hi/lo split of two floats, packed: ret.x = (hi(b)<<16)|hi(a),
// ret.y = lo-pair. hi = truncate-to-bf16; lo = bf16(residual).
__device__ inline uint2 splitpack2(float a, float b) {
  u32 ua = __float_as_uint(a), ub = __float_as_uint(b);
  u32 hi = (ub & 0xFFFF0000u) | (ua >> 16);
  float ra = a - __uint_as_float(ua & 0xFFFF0000u);
  float rb = b - __uint_as_float(ub & 0xFFFF0000u);
  u32 lo = (__float_as_uint(rb) & 0xFFFF0000u) | (__float_as_uint(ra) >> 16);
  return uint2{hi, lo};
}
__device__ inline void split1(float v, u16& hi, u16& lo) {
  u32 u = __float_as_uint(v);
  hi = (u16)(u >> 16);
  float r = v - __uint_as_float(u & 0xFFFF0000u);
  lo = (u16)(__float_as_uint(r) >> 16);
}

// ---------------------------------------------------------------------------
// Pre-split: x -> Xhi/Xlo planes (ws, dead-Ot region), W -> Whi/Wlo (d_out
// used as scratch until gemm2).
// ---------------------------------------------------------------------------
__global__ __launch_bounds__(256) void presplit_xw(
    const float* __restrict__ x, const float* __restrict__ W,
    u16* __restrict__ Xhi, u16* __restrict__ Xlo, u16* __restrict__ Whi,
    u16* __restrict__ Wlo) {
  const u32 g = blockIdx.x * 256 + threadIdx.x;  // 8-elem group
  const float* src;
  u16 *dh, *dl;
  if (g < 262144u) {  // x: 2,097,152 elems
    src = x + (size_t)g * 8;
    dh = Xhi + (size_t)g * 8;
    dl = Xlo + (size_t)g * 8;
  } else {  // W: 786,432 elems
    const u32 gw = g - 262144u;
    src = W + (size_t)gw * 8;
    dh = Whi + (size_t)gw * 8;
    dl = Wlo + (size_t)gw * 8;
  }
  const float4 v0 = *(const float4*)src;
  const float4 v1 = *(const float4*)(src + 4);
  const uint2 p0 = splitpack2(v0.x, v0.y), p1 = splitpack2(v0.z, v0.w);
  const uint2 p2 = splitpack2(v1.x, v1.y), p3 = splitpack2(v1.z, v1.w);
  *(uint4*)dh = uint4{p0.x, p1.x, p2.x, p3.x};
  *(uint4*)dl = uint4{p0.y, p1.y, p2.y, p3.y};
}

// ---------------------------------------------------------------------------
// Pre-split Wo (runs AFTER attn; Q/K/V ws region is dead then).
// ---------------------------------------------------------------------------
__global__ __launch_bounds__(256) void presplit_wo(const float* __restrict__ Wo,
                                                   u16* __restrict__ Wohi,
                                                   u16* __restrict__ Wolo) {
  const u32 g = blockIdx.x * 256 + threadIdx.x;  // 8-elem group, 32768 total
  const float* src = Wo + (size_t)g * 8;
  const float4 v0 = *(const float4*)src;
  const float4 v1 = *(const float4*)(src + 4);
  const uint2 p0 = splitpack2(v0.x, v0.y), p1 = splitpack2(v0.z, v0.w);
  const uint2 p2 = splitpack2(v1.x, v1.y), p3 = splitpack2(v1.z, v1.w);
  *(uint4*)(Wohi + (size_t)g * 8) = uint4{p0.x, p1.x, p2.x, p3.x};
  *(uint4*)(Wolo + (size_t)g * 8) = uint4{p0.y, p1.y, p2.y, p3.y};
}

// ---------------------------------------------------------------------------
// GEMM1 (MFMA) R16: staging via global_load_lds width=16 (m97 2-barrier
// structure; the guide's biggest measured GEMM lever, 646->874 TF vs
// reg-staging at this tile). LDS image per iteration byte-identical to the
// R5 layout: 24 x 1KB lane-linear chunks (6 per wave), per-lane global
// source permuted to match. MFMA reads + epilogue unchanged.
// ---------------------------------------------------------------------------
#define G1_CHUNK(CI, S, D)                                                   \
  {                                                                          \
    const int c_ = wave * 6 + (CI);                                          \
    const u16* pl_ =                                                         \
        (c_ < 8) ? Xhi : (c_ < 16) ? Xlo : (c_ < 20) ? Whi : Wlo;            \
    const int cc_ = (c_ < 16) ? (c_ & 7) : (c_ & 3);                         \
    const int r0_ = (c_ < 16) ? m0 : n0;                                     \
    S = pl_ + (size_t)(r0_ + (cc_ >> 1) * 32) * 512 + (c_ & 1) * 16 +        \
        laneoff;                                                             \
    D = &pool[c_ * 512];                                                     \
  }

__global__ __launch_bounds__(256, 3) void gemm1_mfma(
    const u16* __restrict__ Xhi, const u16* __restrict__ Xlo,
    const u16* __restrict__ Whi, const u16* __restrict__ Wlo,
    const float* __restrict__ bias, u16* __restrict__ Qhi,
    u16* __restrict__ Qlo, u16* __restrict__ Khi, u16* __restrict__ Klo,
    u16* __restrict__ Vthi, u16* __restrict__ Vtlo) {
  // staging uses [0,12288); epilogue overlays up to 18432 (pad-72 rows).
  __shared__ __align__(16) u16 pool[18432];  // 36 KB
  const int tid = threadIdx.x;
  const int wave = tid >> 6, lane = tid & 63, l31 = lane & 31, lhi = lane >> 5;
  const int wm = wave >> 1, wn = wave & 1;
  const int m0 = blockIdx.y * 128, n0 = blockIdx.x * 64;

  // lane-linear chunk: lane L holds row (kg&1)*32+(r&31) -> src offset
  const u32 laneoff = (u32)(lane & 31) * 512 + (u32)(lane >> 5) * 8;
  const u16 *s0, *s1, *s2, *s3, *s4, *s5;
  u16 *d0_, *d1_, *d2_, *d3_, *d4_, *d5_;
  G1_CHUNK(0, s0, d0_);
  G1_CHUNK(1, s1, d1_);
  G1_CHUNK(2, s2, d2_);
  G1_CHUNK(3, s3, d3_);
  G1_CHUNK(4, s4, d4_);
  G1_CHUNK(5, s5, d5_);

  f32x16 acc[2];
#pragma unroll
  for (int r = 0; r < 16; ++r) {
    acc[0][r] = 0.f;
    acc[1][r] = 0.f;
  }

  for (int k0 = 0; k0 < 512; k0 += 32) {
    gload16(s0 + k0, d0_);
    gload16(s1 + k0, d1_);
    gload16(s2 + k0, d2_);
    gload16(s3 + k0, d3_);
    gload16(s4 + k0, d4_);
    gload16(s5 + k0, d5_);
    __syncthreads();  // drains vmcnt -> tile resident
#pragma unroll
    for (int t = 0; t < 2; ++t) {
      const bf16x8 bh =
          *(const bf16x8*)&pool[8192 + (((0 * 2 + wn) * 2 + t) * 64 + lane) * 8];
      const bf16x8 bl =
          *(const bf16x8*)&pool[8192 + (((1 * 2 + wn) * 2 + t) * 64 + lane) * 8];
#pragma unroll
      for (int ti = 0; ti < 2; ++ti) {
        const bf16x8 ah =
            *(const bf16x8*)&pool[(((0 * 4 + wm * 2 + ti) * 2 + t) * 64 + lane) * 8];
        const bf16x8 al =
            *(const bf16x8*)&pool[(((1 * 4 + wm * 2 + ti) * 2 + t) * 64 + lane) * 8];
        acc[ti] = MFMA32(ah, bh, acc[ti], 0, 0, 0);
        acc[ti] = MFMA32(ah, bl, acc[ti], 0, 0, 0);
        acc[ti] = MFMA32(al, bh, acc[ti], 0, 0, 0);
      }
    }
    __syncthreads();  // all waves done reading before next overwrite
  }

  // ---- epilogue: LDS-staged coalesced stores (unchanged) ----
  const int n = n0 + wn * 32 + l31;
  const float bn = bias[n];
  const int h = n0 / 192;
  const int t3 = (n0 % 192) / 64;
  const int dh = wn * 32 + l31;
  const int batch = m0 >> 11;
  const int s0e = m0 & 2047;
  const int hbq = h * 2 + batch;

#pragma unroll
  for (int ti = 0; ti < 2; ++ti)
#pragma unroll
    for (int r = 0; r < 16; ++r) {
      const int tl = wm * 64 + ti * 32 + (r & 3) + 8 * (r >> 2) + 4 * lhi;
      float val = acc[ti][r] + bn;
      if (t3 == 0) val *= 0.125f;  // fold logit scale into Q
      u16 hi, lo;
      split1(val, hi, lo);
      pool[tl * 72 + dh] = hi;
      pool[9216 + tl * 72 + dh] = lo;
    }
  __syncthreads();

  u16 *d0, *d1;
  if (t3 == 0) {
    d0 = Qhi;
    d1 = Qlo;
  } else if (t3 == 1) {
    d0 = Khi;
    d1 = Klo;
  } else {
    d0 = Vthi;
    d1 = Vtlo;
  }

  if (t3 != 2) {
    const size_t base = ((size_t)hbq * 2048 + s0e) * 64;
#pragma unroll
    for (int p = 0; p < 2; ++p) {
      u16* dst = (p ? d1 : d0) + base;
#pragma unroll
      for (int j = 0; j < 4; ++j) {
        const int g = tid * 32 + j * 8;
        const int token = g >> 6, dh8 = g & 63;
        *(uint4*)(dst + g) = *(const uint4*)&pool[p * 9216 + token * 72 + dh8];
      }
    }
  } else {
    const int d = tid >> 2, tp = (tid & 3) * 32;
#pragma unroll
    for (int p = 0; p < 2; ++p) {
      u16* dst = (p ? d1 : d0) + ((size_t)hbq * 64 + d) * 2048 + s0e + tp;
      u32 w[16];
#pragma unroll
      for (int j = 0; j < 16; ++j) {
        const u16 a = pool[p * 9216 + (tp + 2 * j) * 72 + d];
        const u16 b2 = pool[p * 9216 + (tp + 2 * j + 1) * 72 + d];
        w[j] = (u32)a | ((u32)b2 << 16);
      }
#pragma unroll
      for (int j = 0; j < 4; ++j)
        *(uint4*)(dst + j * 8) =
            uint4{w[4 * j], w[4 * j + 1], w[4 * j + 2], w[4 * j + 3]};
    }
  }
}

// ---------------------------------------------------------------------------
// MFMA flash attention: R7 version unchanged (110.5 us; defer-max + hs-fold
// + setprio on the proven R12 schedule).
// ---------------------------------------------------------------------------
constexpr int KF0 = 8320;   // u16 idx; SMs = [0,8320) u16 (64x65 f32)
constexpr int VF0 = 16512;  // Kf 8192 u16 (16 KB)
constexpr int PF0 = 24704;  // Vf 8192 u16 (16 KB); Pf 8192 u16 (16 KB)

#define ISSUE_TILE(KT)                                   \
  {                                                      \
    const float* sp_ = shr + (KT);                       \
    const float* mp_ = mkr + (KT);                       \
    pS0 = *(const float4*)(sp_);                         \
    pS1 = *(const float4*)(sp_ + 4);                     \
    pS2 = *(const float4*)(sp_ + 8);                     \
    pS3 = *(const float4*)(sp_ + 12);                    \
    pM0 = *(const float4*)(mp_);                         \
    pM1 = *(const float4*)(mp_ + 4);                     \
    pM2 = *(const float4*)(mp_ + 8);                     \
    pM3 = *(const float4*)(mp_ + 12);                    \
    const u16* h_ = kvsrc_hi + (size_t)(KT) * ktmul;     \
    const u16* l_ = kvsrc_lo + (size_t)(KT) * ktmul;     \
    pK0 = *(const uint4*)(h_);                           \
    pK1 = *(const uint4*)(l_);                           \
    pK2 = *(const uint4*)(h_ + 8);                       \
    pK3 = *(const uint4*)(l_ + 8);                       \
    pK4 = *(const uint4*)(h_ + 16);                      \
    pK5 = *(const uint4*)(l_ + 16);                      \
    pK6 = *(const uint4*)(h_ + 24);                      \
    pK7 = *(const uint4*)(l_ + 24);                      \
  }

// hs folded: store hs*shift (or 1e13 sentinel) so logits are a bare subtract.
#define COMMIT_TILE()                                    \
  {                                                      \
    smd[0 * 65] = (pM0.x != 0.f) ? hs * pS0.x : 1e13f;   \
    smd[1 * 65] = (pM0.y != 0.f) ? hs * pS0.y : 1e13f;   \
    smd[2 * 65] = (pM0.z != 0.f) ? hs * pS0.z : 1e13f;   \
    smd[3 * 65] = (pM0.w != 0.f) ? hs * pS0.w : 1e13f;   \
    smd[4 * 65] = (pM1.x != 0.f) ? hs * pS1.x : 1e13f;   \
    smd[5 * 65] = (pM1.y != 0.f) ? hs * pS1.y : 1e13f;   \
    smd[6 * 65] = (pM1.z != 0.f) ? hs * pS1.z : 1e13f;   \
    smd[7 * 65] = (pM1.w != 0.f) ? hs * pS1.w : 1e13f;   \
    smd[8 * 65] = (pM2.x != 0.f) ? hs * pS2.x : 1e13f;   \
    smd[9 * 65] = (pM2.y != 0.f) ? hs * pS2.y : 1e13f;   \
    smd[10 * 65] = (pM2.z != 0.f) ? hs * pS2.z : 1e13f;  \
    smd[11 * 65] = (pM2.w != 0.f) ? hs * pS2.w : 1e13f;  \
    smd[12 * 65] = (pM3.x != 0.f) ? hs * pS3.x : 1e13f;  \
    smd[13 * 65] = (pM3.y != 0.f) ? hs * pS3.y : 1e13f;  \
    smd[14 * 65] = (pM3.z != 0.f) ? hs * pS3.z : 1e13f;  \
    smd[15 * 65] = (pM3.w != 0.f) ? hs * pS3.w : 1e13f;  \
    *(uint4*)(kvdst + 0) = pK0;                          \
    *(uint4*)(kvdst + 4096) = pK1;                       \
    *(uint4*)(kvdst + 256) = pK2;                        \
    *(uint4*)(kvdst + 4096 + 256) = pK3;                 \
    *(uint4*)(kvdst + 512) = pK4;                        \
    *(uint4*)(kvdst + 4096 + 512) = pK5;                 \
    *(uint4*)(kvdst + 768) = pK6;                        \
    *(uint4*)(kvdst + 4096 + 768) = pK7;                 \
  }

__global__ __launch_bounds__(256, 2) void attn_mfma(
    const u16* __restrict__ Qhi, const u16* __restrict__ Qlo,
    const u16* __restrict__ Khi, const u16* __restrict__ Klo,
    const u16* __restrict__ Vthi, const u16* __restrict__ Vtlo,
    const float* __restrict__ shift, const float* __restrict__ mask,
    u16* __restrict__ Othi, u16* __restrict__ Otlo) {
  const int head = blockIdx.z, b = blockIdx.y, qb = blockIdx.x;
  const int tid = threadIdx.x;
  const int wave = tid >> 6;
  const int wq = wave >> 1, wk = wave & 1;
  const int lane = tid & 63;
  const int l31 = lane & 31, lhi = lane >> 5;

  __shared__ __align__(16) u16 smem[32896];  // 65792 B
  float* SMs = (float*)smem;                 // [64][65] transposed [k][q]
  u16* Pw = smem + PF0 + wave * 2048;        // wave P chunk: hi | lo+1024

  const size_t hb = (size_t)head * Bc + b;
  const int ql = wq * 32 + l31;
  const int qg = qb * 64 + ql;

  // Q B-frags (pre-scaled): n=q, k = t*16 + lhi*8 + j
  bf16x8 qf[2][4];
  {
    const size_t qbase = (hb * Sc + qg) * DHc;
#pragma unroll
    for (int t = 0; t < 4; ++t) {
      qf[0][t] = *(const bf16x8*)(Qhi + qbase + t * 16 + lhi * 8);
      qf[1][t] = *(const bf16x8*)(Qlo + qbase + t * 16 + lhi * 8);
    }
  }
  const float hs = exp2f(-(float)head);

  // SM staging map: thread -> row q = tid>>2, cols (tid&3)*16 .. +15
  const int smq = tid >> 2, smk = (tid & 3) * 16;
  const float* shr = shift + ((size_t)b * Sc + qb * 64 + smq) * Sc + smk;
  const float* mkr = mask + ((size_t)b * Sc + qb * 64 + smq) * Sc + smk;
  float* const smd = SMs + (size_t)smk * 65 + smq;

  // K staging (waves wq==0): 32 keys x 64 dh, half wk
  const int kr = lane >> 1, kh2 = lane & 1;
  const size_t kfix = (hb * Sc + wk * 32 + kr) * 64 + kh2 * 32;
  // V staging (waves wq==1): lane = dh row
  const size_t vfix = (hb * 64 + lane) * 2048 + wk * 32;
  const int vmt = lane >> 5, vdl = lane & 31;

  const u16* const kvsrc_hi = (wq == 0) ? (Khi + kfix) : (Vthi + vfix);
  const u16* const kvsrc_lo = (wq == 0) ? (Klo + kfix) : (Vtlo + vfix);
  const int ktmul = (wq == 0) ? 64 : 1;
  u16* const kvdst = (wq == 0)
                         ? &smem[KF0 + (wk * 4 + kh2 * 2) * 512 + kr * 8]
                         : &smem[VF0 + (wk * 4 + vmt * 2) * 512 + vdl * 8];

  float m_run = -INFINITY, l_run = 0.f;
  f32x16 o0, o1;
#pragma unroll
  for (int i = 0; i < 16; ++i) {
    o0[i] = 0.f;
    o1[i] = 0.f;
  }

  // T14 prefetch registers (named; never indexed -> stay in VGPRs)
  float4 pS0, pS1, pS2, pS3, pM0, pM1, pM2, pM3;
  uint4 pK0, pK1, pK2, pK3, pK4, pK5, pK6, pK7;

  ISSUE_TILE(0);
  for (int it = 0; it < 32; ++it) {
    COMMIT_TILE();  // regs -> LDS
    __syncthreads();
    if (it < 31) ISSUE_TILE(it * 64 + 64);  // overlap next HBM fetch w/ compute

    // ---- S^T = K·Q^T (m=key32, n=q32): Khi*Qhi + Khi*Qlo + Klo*Qhi
    f32x16 s;
#pragma unroll
    for (int i = 0; i < 16; ++i) s[i] = 0.f;
    __builtin_amdgcn_s_setprio(1);
#pragma unroll
    for (int t = 0; t < 4; ++t) {
      const bf16x8 kh = *(const bf16x8*)&smem[KF0 +
          (((0 * 2 + wk) * 4 + t) * 64 + lane) * 8];
      const bf16x8 kl = *(const bf16x8*)&smem[KF0 +
          (((1 * 2 + wk) * 4 + t) * 64 + lane) * 8];
      s = MFMA32(kh, qf[0][t], s, 0, 0, 0);
      s = MFMA32(kh, qf[1][t], s, 0, 0, 0);
      s = MFMA32(kl, qf[0][t], s, 0, 0, 0);
    }
    __builtin_amdgcn_s_setprio(0);

    // ---- logits from SMs (hs pre-folded) + online softmax w/ defer-max
    float p[16];
    float kmax = -INFINITY;
#pragma unroll
    for (int c = 0; c < 4; ++c) {
#pragma unroll
      for (int e = 0; e < 4; ++e) {
        const int kl_ = wk * 32 + c * 8 + lhi * 4 + e;
        const float lg = s[4 * c + e] - SMs[(size_t)kl_ * 65 + ql];
        p[4 * c + e] = lg;
        kmax = fmaxf(kmax, lg);
      }
    }
    kmax = fmaxf(kmax, __shfl_xor(kmax, 32, 64));

    // T13 defer-max: only rescale when the running max grew by > 8.
    if (!__all(kmax <= m_run + 8.f)) {
      const float mnew = fmaxf(m_run, kmax);
      const float alpha = __expf(m_run - mnew);
      l_run *= alpha;
      m_run = mnew;
#pragma unroll
      for (int i = 0; i < 16; ++i) {
        o0[i] *= alpha;
        o1[i] *= alpha;
      }
    }
    float rsum = 0.f;
#pragma unroll
    for (int r = 0; r < 16; ++r) {
      p[r] = __expf(p[r] - m_run);
      rsum += p[r];
    }
    rsum += __shfl_xor(rsum, 32, 64);
    l_run += rsum;

    // ---- P -> own LDS chunk (same-wave DS ordering; no barrier needed)
#pragma unroll
    for (int c = 0; c < 4; ++c) {
      const uint2 s01 = splitpack2(p[4 * c + 0], p[4 * c + 1]);
      const uint2 s23 = splitpack2(p[4 * c + 2], p[4 * c + 3]);
      const int t = c >> 1, lh = c & 1;
      const int bi = (t * 64 + lh * 32 + l31) * 8 + lhi * 4;
      *(uint2*)&Pw[bi] = uint2{s01.x, s23.x};
      *(uint2*)&Pw[1024 + bi] = uint2{s01.y, s23.y};
    }

    // ---- O^T += V^T · P^T
    __builtin_amdgcn_s_setprio(1);
#pragma unroll
    for (int t = 0; t < 2; ++t) {
      const bf16x8 ph = *(const bf16x8*)&Pw[(t * 64 + lane) * 8];
      const bf16x8 pl_ = *(const bf16x8*)&Pw[1024 + (t * 64 + lane) * 8];
      bf16x8 vh = *(const bf16x8*)&smem[VF0 +
          ((((0 * 2 + wk) * 2 + 0) * 2 + t) * 64 + lane) * 8];
      bf16x8 vl = *(const bf16x8*)&smem[VF0 +
          ((((1 * 2 + wk) * 2 + 0) * 2 + t) * 64 + lane) * 8];
      o0 = MFMA32(vh, ph, o0, 0, 0, 0);
      o0 = MFMA32(vh, pl_, o0, 0, 0, 0);
      o0 = MFMA32(vl, ph, o0, 0, 0, 0);
      vh = *(const bf16x8*)&smem[VF0 +
          ((((0 * 2 + wk) * 2 + 1) * 2 + t) * 64 + lane) * 8];
      vl = *(const bf16x8*)&smem[VF0 +
          ((((1 * 2 + wk) * 2 + 1) * 2 + t) * 64 + lane) * 8];
      o1 = MFMA32(vh, ph, o1, 0, 0, 0);
      o1 = MFMA32(vh, pl_, o1, 0, 0, 0);
      o1 = MFMA32(vl, ph, o1, 0, 0, 0);
    }
    __builtin_amdgcn_s_setprio(0);
    __syncthreads();
  }

  // ---- merge wk=0/1 (same wq) through LDS (overlays Kf/Vf, dead now)
  float* mL = (float*)(smem + KF0);  // 64
  float* lL = mL + 64;               // 64
  float* Om = lL + 64;               // [2][64][33]
  if (wk == 1) {
    if (lhi == 0) {
      mL[wq * 32 + l31] = m_run;
      lL[wq * 32 + l31] = l_run;
    }
#pragma unroll
    for (int mt = 0; mt < 2; ++mt)
#pragma unroll
      for (int r = 0; r < 16; ++r) {
        const int row = mt * 32 + (r & 3) + 8 * (r >> 2) + 4 * lhi;
        Om[(wq * 64 + row) * 33 + l31] = (mt ? o1[r] : o0[r]);
      }
  }
  __syncthreads();
  if (wk == 0) {
    const float m1 = mL[wq * 32 + l31];
    const float l1v = lL[wq * 32 + l31];
    const float mst = fmaxf(m_run, m1);
    const float a0 = __expf(m_run - mst), a1 = __expf(m1 - mst);
    const float inv = 1.f / (a0 * l_run + a1 * l1v);
    const int tok = b * 2048 + qg;
#pragma unroll
    for (int mt = 0; mt < 2; ++mt)
#pragma unroll
      for (int r = 0; r < 16; ++r) {
        const int row = mt * 32 + (r & 3) + 8 * (r >> 2) + 4 * lhi;
        const float val = (a0 * (mt ? o1[r] : o0[r]) +
                           a1 * Om[(wq * 64 + row) * 33 + l31]) *
                          inv;
        const int d = head * 64 + row;
        u16 hi, lo;
        split1(val, hi, lo);
        const size_t idx = ((size_t)(d >> 3) * 4096 + tok) * 8 + (d & 7);
        Othi[idx] = hi;
        Otlo[idx] = lo;
      }
  }
}

// ---------------------------------------------------------------------------
// GEMM2 (MFMA) R16: staging via global_load_lds width=16. 16 x 1KB chunks
// (4 per wave; waves 0-1 stage A planes with k-stride 4096, waves 2-3 stage
// B planes with k-stride 1). LDS image identical to the old Af/Bf layout.
// ---------------------------------------------------------------------------
#define G2_CHUNK(CI, S, D)                                                   \
  {                                                                          \
    const int c_ = wave * 4 + (CI);                                          \
    if (c_ < 8) {                                                            \
      const int p_ = c_ >> 2, tt_ = (c_ >> 1) & 1, ch_ = c_ & 1;             \
      S = (p_ ? Otlo : Othi) +                                               \
          (size_t)(ch_ * 2 * 4096 + m0 + tt_ * 32) * 8 + laneA;              \
    } else {                                                                 \
      const int cc_ = c_ - 8;                                                \
      const int p_ = cc_ >> 2, nt_ = (cc_ >> 1) & 1, ch_ = cc_ & 1;          \
      S = (p_ ? Wolo : Wohi) + (size_t)(n0 + nt_ * 32) * 512 + ch_ * 16 +    \
          laneB;                                                             \
    }                                                                        \
    D = &pool2[c_ * 512];                                                    \
  }

__global__ __launch_bounds__(256, 2) void gemm2_mfma(
    const u16* __restrict__ Othi, const u16* __restrict__ Otlo,
    const u16* __restrict__ Wohi, const u16* __restrict__ Wolo,
    const float* __restrict__ bo, float* __restrict__ out) {
  __shared__ __align__(16) u16 pool2[8192];  // 16 KB
  const int tid = threadIdx.x;
  const int wave = tid >> 6, lane = tid & 63, l31 = lane & 31, lhi = lane >> 5;
  const int wm = wave >> 1, wn = wave & 1;
  const int m0 = blockIdx.y * 64, n0 = blockIdx.x * 64;

  const u32 laneA = (u32)(lane >> 5) * 32768 + (u32)(lane & 31) * 8;
  const u32 laneB = (u32)(lane & 31) * 512 + (u32)(lane >> 5) * 8;
  const size_t ktm = (wave < 2) ? 4096 : 1;  // A chunks stride k*4096, B k

  const u16 *s0, *s1, *s2, *s3;
  u16 *d0_, *d1_, *d2_, *d3_;
  G2_CHUNK(0, s0, d0_);
  G2_CHUNK(1, s1, d1_);
  G2_CHUNK(2, s2, d2_);
  G2_CHUNK(3, s3, d3_);

  f32x16 acc;
#pragma unroll
  for (int r = 0; r < 16; ++r) acc[r] = 0.f;

  for (int k0 = 0; k0 < 512; k0 += 32) {
    const size_t ko = (size_t)k0 * ktm;
    gload16(s0 + ko, d0_);
    gload16(s1 + ko, d1_);
    gload16(s2 + ko, d2_);
    gload16(s3 + ko, d3_);
    __syncthreads();
#pragma unroll
    for (int t = 0; t < 2; ++t) {
      const bf16x8 ah = *(const bf16x8*)&pool2[(wm * 2 + t) * 512 + lane * 8];
      const bf16x8 al =
          *(const bf16x8*)&pool2[2048 + (wm * 2 + t) * 512 + lane * 8];
      const bf16x8 bh =
          *(const bf16x8*)&pool2[4096 + (wn * 2 + t) * 512 + lane * 8];
      const bf16x8 bl =
          *(const bf16x8*)&pool2[6144 + (wn * 2 + t) * 512 + lane * 8];
      acc = MFMA32(ah, bh, acc, 0, 0, 0);
      acc = MFMA32(ah, bl, acc, 0, 0, 0);
      acc = MFMA32(al, bh, acc, 0, 0, 0);
    }
    __syncthreads();
  }

  const int n = n0 + wn * 32 + l31;
  const float bn = bo[n];
#pragma unroll
  for (int r = 0; r < 16; ++r) {
    const int m = m0 + wm * 32 + (r & 3) + 8 * (r >> 2) + 4 * lhi;
    out[(size_t)m * 512 + n] = acc[r] + bn;
  }
}

// ---------------------------------------------------------------------------
extern "C" void kernel_launch(void* const* d_in, const int* in_sizes, int n_in,
                              void* d_out, int out_size, void* d_ws,
                              size_t ws_size, hipStream_t stream) {
  const float* x = (const float*)d_in[0];
  const float* shift = (const float*)d_in[1];
  const float* mask = (const float*)d_in[2];
  const float* W = (const float*)d_in[3];
  const float* b = (const float*)d_in[4];
  const float* Wo = (const float*)d_in[5];
  const float* bo = (const float*)d_in[6];
  float* out = (float*)d_out;

  // ws (32 MiB): [0,6P) Q/K/V hi+lo planes (dead after attn; Wo planes reuse
  // the head of this region), [6P,8P) X planes (phase 1) then Ot planes.
  // W planes live in d_out until gemm2.
  const size_t P = (size_t)Hc * Bc * Sc * DHc;  // 2,097,152
  u16* ws0 = (u16*)d_ws;
  u16* Qhi = ws0;
  u16* Qlo = ws0 + P;
  u16* Khi = ws0 + 2 * P;
  u16* Klo = ws0 + 3 * P;
  u16* Vthi = ws0 + 4 * P;
  u16* Vtlo = ws0 + 5 * P;
  u16* Othi = ws0 + 6 * P;
  u16* Otlo = ws0 + 7 * P;
  u16* Xhi = ws0 + 6 * P;  // aliases Ot region (dead until attn)
  u16* Xlo = ws0 + 7 * P;
  u16* Whi = (u16*)out;  // d_out as scratch until gemm2
  u16* Wlo = (u16*)out + 786432;
  u16* Wohi = ws0;                // aliases Q region (dead after attn)
  u16* Wolo = ws0 + 262144;

  // 0) pre-split x and W to bf16 hi/lo planes
  presplit_xw<<<dim3(1408), 256, 0, stream>>>(x, W, Xhi, Xlo, Whi, Wlo);

  // 1) QKV projection (MFMA, global_load_lds staging; Q pre-scaled)
  gemm1_mfma<<<dim3(NQKV / 64, (Bc * Sc) / 128), 256, 0, stream>>>(
      Xhi, Xlo, Whi, Wlo, b, Qhi, Qlo, Khi, Klo, Vthi, Vtlo);

  // 2) MFMA flash attention (R7) -> Ot planes
  attn_mfma<<<dim3(Sc / 64, Bc, Hc), 256, 0, stream>>>(
      Qhi, Qlo, Khi, Klo, Vthi, Vtlo, shift, mask, Othi, Otlo);

  // 2b) pre-split Wo into the now-dead Q region
  presplit_wo<<<dim3(128), 256, 0, stream>>>(Wo, Wohi, Wolo);

  // 3) output projection (MFMA, global_load_lds staging) -> out
  gemm2_mfma<<<dim3(Dc / 64, (Bc * Sc) / 64), 256, 0, stream>>>(
      Othi, Otlo, Wohi, Wolo, bo, out);
}

// Round 9
// 254.372 us; speedup vs baseline: 1.0215x; 1.0215x over previous
//
#include <hip/hip_runtime.h>
#include <math.h>

// Problem constants (fixed by reference)
constexpr int Bc = 2, Sc = 2048, Dc = 512, Hc = 8, DHc = 64;
constexpr int NQKV = 3 * Dc;  // 1536

typedef unsigned short u16;
typedef unsigned int u32;
typedef __attribute__((ext_vector_type(8))) __bf16 bf16x8;
typedef __attribute__((ext_vector_type(16))) float f32x16;

#define MFMA32 __builtin_amdgcn_mfma_f32_32x32x16_bf16

// Truncation hi/lo split of two floats, packed: ret.x = (hi(b)<<16)|hi(a),
// ret.y = lo-pair. hi = truncate-to-bf16; lo = bf16(residual).
__device__ inline uint2 splitpack2(float a, float b) {
  u32 ua = __float_as_uint(a), ub = __float_as_uint(b);
  u32 hi = (ub & 0xFFFF0000u) | (ua >> 16);
  float ra = a - __uint_as_float(ua & 0xFFFF0000u);
  float rb = b - __uint_as_float(ub & 0xFFFF0000u);
  u32 lo = (__float_as_uint(rb) & 0xFFFF0000u) | (__float_as_uint(ra) >> 16);
  return uint2{hi, lo};
}
__device__ inline void split1(float v, u16& hi, u16& lo) {
  u32 u = __float_as_uint(v);
  hi = (u16)(u >> 16);
  float r = v - __uint_as_float(u & 0xFFFF0000u);
  lo = (u16)(__float_as_uint(r) >> 16);
}

// ---------------------------------------------------------------------------
// Pre-split: x -> Xhi/Xlo planes (ws, dead-Ot region), W -> Whi/Wlo (d_out
// used as scratch until gemm2).
// ---------------------------------------------------------------------------
__global__ __launch_bounds__(256) void presplit_xw(
    const float* __restrict__ x, const float* __restrict__ W,
    u16* __restrict__ Xhi, u16* __restrict__ Xlo, u16* __restrict__ Whi,
    u16* __restrict__ Wlo) {
  const u32 g = blockIdx.x * 256 + threadIdx.x;  // 8-elem group
  const float* src;
  u16 *dh, *dl;
  if (g < 262144u) {  // x: 2,097,152 elems
    src = x + (size_t)g * 8;
    dh = Xhi + (size_t)g * 8;
    dl = Xlo + (size_t)g * 8;
  } else {  // W: 786,432 elems
    const u32 gw = g - 262144u;
    src = W + (size_t)gw * 8;
    dh = Whi + (size_t)gw * 8;
    dl = Wlo + (size_t)gw * 8;
  }
  const float4 v0 = *(const float4*)src;
  const float4 v1 = *(const float4*)(src + 4);
  const uint2 p0 = splitpack2(v0.x, v0.y), p1 = splitpack2(v0.z, v0.w);
  const uint2 p2 = splitpack2(v1.x, v1.y), p3 = splitpack2(v1.z, v1.w);
  *(uint4*)dh = uint4{p0.x, p1.x, p2.x, p3.x};
  *(uint4*)dl = uint4{p0.y, p1.y, p2.y, p3.y};
}

// ---------------------------------------------------------------------------
// Pre-split Wo (runs AFTER attn; Q/K/V ws region is dead then).
// ---------------------------------------------------------------------------
__global__ __launch_bounds__(256) void presplit_wo(const float* __restrict__ Wo,
                                                   u16* __restrict__ Wohi,
                                                   u16* __restrict__ Wolo) {
  const u32 g = blockIdx.x * 256 + threadIdx.x;  // 8-elem group, 32768 total
  const float* src = Wo + (size_t)g * 8;
  const float4 v0 = *(const float4*)src;
  const float4 v1 = *(const float4*)(src + 4);
  const uint2 p0 = splitpack2(v0.x, v0.y), p1 = splitpack2(v0.z, v0.w);
  const uint2 p2 = splitpack2(v1.x, v1.y), p3 = splitpack2(v1.z, v1.w);
  *(uint4*)(Wohi + (size_t)g * 8) = uint4{p0.x, p1.x, p2.x, p3.x};
  *(uint4*)(Wolo + (size_t)g * 8) = uint4{p0.y, p1.y, p2.y, p3.y};
}

// ---------------------------------------------------------------------------
// GEMM1 (MFMA) R17: tile 128x128 (was 128x64), BK=32, 4 waves (2x2), each
// wave owns a 64x64 output (acc[2][2]). MFMA-per-barrier doubles (12->24),
// B-panel traffic halves, grid 768->384 blocks. Staging = presplit-plane
// uint4 copies with named-register prefetch (proven R5 pattern); index
// formulas preserved (B region adopts A's 4-subtile structure). Epilogue
// runs twice (one pass per 64-col half).
// LDS: A [0,8192) plane-stride 4096; B [8192,16384) plane-stride 4096;
//      epilogue overlays [0,18432) (pad-72 rows).
// ---------------------------------------------------------------------------
#define G1_ISSUE(K0)                          \
  {                                           \
    a0h = *(const uint4*)(srcA0h + (K0));     \
    a0l = *(const uint4*)(srcA0l + (K0));     \
    a1h = *(const uint4*)(srcA1h + (K0));     \
    a1l = *(const uint4*)(srcA1l + (K0));     \
    b0h = *(const uint4*)(srcB0h + (K0));     \
    b0l = *(const uint4*)(srcB0l + (K0));     \
    b1h = *(const uint4*)(srcB1h + (K0));     \
    b1l = *(const uint4*)(srcB1l + (K0));     \
  }
#define G1_COMMIT()                           \
  {                                           \
    *(uint4*)dA0h = a0h;                      \
    *(uint4*)dA0l = a0l;                      \
    *(uint4*)dA1h = a1h;                      \
    *(uint4*)dA1l = a1l;                      \
    *(uint4*)dB0h = b0h;                      \
    *(uint4*)dB0l = b0l;                      \
    *(uint4*)dB1h = b1h;                      \
    *(uint4*)dB1l = b1l;                      \
  }

__global__ __launch_bounds__(256, 3) void gemm1_mfma(
    const u16* __restrict__ Xhi, const u16* __restrict__ Xlo,
    const u16* __restrict__ Whi, const u16* __restrict__ Wlo,
    const float* __restrict__ bias, u16* __restrict__ Qhi,
    u16* __restrict__ Qlo, u16* __restrict__ Khi, u16* __restrict__ Klo,
    u16* __restrict__ Vthi, u16* __restrict__ Vtlo) {
  __shared__ __align__(16) u16 pool[18432];  // 36 KB
  const int tid = threadIdx.x;
  const int wave = tid >> 6, lane = tid & 63, l31 = lane & 31, lhi = lane >> 5;
  const int wm = wave >> 1, wn = wave & 1;
  const int m0 = blockIdx.y * 128, n0 = blockIdx.x * 128;

  // staging map: row mA = tid>>2 (0..63; +64 for the *1 pointers), kg = tid&3
  const int mA = tid >> 2, kgA = tid & 3;
  const int rowA = (kgA & 1) * 32 + (mA & 31);
  const int base0 = (mA >> 5) * 1024 + (kgA >> 1) * 512 + rowA * 8;
  u16* const dA0h = &pool[base0];
  u16* const dA0l = dA0h + 4096;
  u16* const dA1h = dA0h + 2048;  // m-subtiles 2,3
  u16* const dA1l = dA1h + 4096;
  u16* const dB0h = dA0h + 8192;
  u16* const dB0l = dB0h + 4096;
  u16* const dB1h = dB0h + 2048;  // n-subtiles 2,3
  u16* const dB1l = dB1h + 4096;
  const u16* const srcA0h = Xhi + (size_t)(m0 + mA) * 512 + kgA * 8;
  const u16* const srcA0l = Xlo + (size_t)(m0 + mA) * 512 + kgA * 8;
  const u16* const srcA1h = srcA0h + 64 * 512;
  const u16* const srcA1l = srcA0l + 64 * 512;
  const u16* const srcB0h = Whi + (size_t)(n0 + mA) * 512 + kgA * 8;
  const u16* const srcB0l = Wlo + (size_t)(n0 + mA) * 512 + kgA * 8;
  const u16* const srcB1h = srcB0h + 64 * 512;
  const u16* const srcB1l = srcB0l + 64 * 512;

  f32x16 acc[2][2];
#pragma unroll
  for (int r = 0; r < 16; ++r) {
    acc[0][0][r] = 0.f;
    acc[0][1][r] = 0.f;
    acc[1][0][r] = 0.f;
    acc[1][1][r] = 0.f;
  }

  uint4 a0h, a0l, a1h, a1l, b0h, b0l, b1h, b1l;
  G1_ISSUE(0);
  for (int k0 = 0; k0 < 512; k0 += 32) {
    G1_COMMIT();
    __syncthreads();
    if (k0 < 480) G1_ISSUE(k0 + 32);
#pragma unroll
    for (int t = 0; t < 2; ++t) {
      const bf16x8 bh0 =
          *(const bf16x8*)&pool[8192 + (wn * 2 + 0) * 1024 + t * 512 + lane * 8];
      const bf16x8 bl0 =
          *(const bf16x8*)&pool[12288 + (wn * 2 + 0) * 1024 + t * 512 + lane * 8];
      const bf16x8 bh1 =
          *(const bf16x8*)&pool[8192 + (wn * 2 + 1) * 1024 + t * 512 + lane * 8];
      const bf16x8 bl1 =
          *(const bf16x8*)&pool[12288 + (wn * 2 + 1) * 1024 + t * 512 + lane * 8];
#pragma unroll
      for (int mi = 0; mi < 2; ++mi) {
        const bf16x8 ah =
            *(const bf16x8*)&pool[(wm * 2 + mi) * 1024 + t * 512 + lane * 8];
        const bf16x8 al =
            *(const bf16x8*)&pool[4096 + (wm * 2 + mi) * 1024 + t * 512 + lane * 8];
        acc[mi][0] = MFMA32(ah, bh0, acc[mi][0], 0, 0, 0);
        acc[mi][0] = MFMA32(ah, bl0, acc[mi][0], 0, 0, 0);
        acc[mi][0] = MFMA32(al, bh0, acc[mi][0], 0, 0, 0);
        acc[mi][1] = MFMA32(ah, bh1, acc[mi][1], 0, 0, 0);
        acc[mi][1] = MFMA32(ah, bl1, acc[mi][1], 0, 0, 0);
        acc[mi][1] = MFMA32(al, bh1, acc[mi][1], 0, 0, 0);
      }
    }
    __syncthreads();
  }

  // ---- epilogue: two passes, one per 64-col half (own h/t3/destination) ----
  const int batch = m0 >> 11;
  const int s0e = m0 & 2047;

#pragma unroll
  for (int ph = 0; ph < 2; ++ph) {
    const int nn0 = n0 + ph * 64;
    const int h = nn0 / 192;
    const int t3 = (nn0 % 192) / 64;
    const int hbq = h * 2 + batch;

    if (wn == ph) {
#pragma unroll
      for (int ni = 0; ni < 2; ++ni) {
        const float bn = bias[nn0 + ni * 32 + l31];
        const int dh = ni * 32 + l31;
#pragma unroll
        for (int mi = 0; mi < 2; ++mi)
#pragma unroll
          for (int r = 0; r < 16; ++r) {
            const int tl = wm * 64 + mi * 32 + (r & 3) + 8 * (r >> 2) + 4 * lhi;
            float val = acc[mi][ni][r] + bn;
            if (t3 == 0) val *= 0.125f;  // fold logit scale into Q
            u16 hi, lo;
            split1(val, hi, lo);
            pool[tl * 72 + dh] = hi;
            pool[9216 + tl * 72 + dh] = lo;
          }
      }
    }
    __syncthreads();

    u16 *d0, *d1;
    if (t3 == 0) {
      d0 = Qhi;
      d1 = Qlo;
    } else if (t3 == 1) {
      d0 = Khi;
      d1 = Klo;
    } else {
      d0 = Vthi;
      d1 = Vtlo;
    }

    if (t3 != 2) {
      const size_t base = ((size_t)hbq * 2048 + s0e) * 64;
#pragma unroll
      for (int p = 0; p < 2; ++p) {
        u16* dst = (p ? d1 : d0) + base;
#pragma unroll
        for (int j = 0; j < 4; ++j) {
          const int g = tid * 32 + j * 8;
          const int token = g >> 6, dh8 = g & 63;
          *(uint4*)(dst + g) =
              *(const uint4*)&pool[p * 9216 + token * 72 + dh8];
        }
      }
    } else {
      const int d = tid >> 2, tp = (tid & 3) * 32;
#pragma unroll
      for (int p = 0; p < 2; ++p) {
        u16* dst = (p ? d1 : d0) + ((size_t)hbq * 64 + d) * 2048 + s0e + tp;
        u32 w[16];
#pragma unroll
        for (int j = 0; j < 16; ++j) {
          const u16 a = pool[p * 9216 + (tp + 2 * j) * 72 + d];
          const u16 b2 = pool[p * 9216 + (tp + 2 * j + 1) * 72 + d];
          w[j] = (u32)a | ((u32)b2 << 16);
        }
#pragma unroll
        for (int j = 0; j < 4; ++j)
          *(uint4*)(dst + j * 8) =
              uint4{w[4 * j], w[4 * j + 1], w[4 * j + 2], w[4 * j + 3]};
      }
    }
    __syncthreads();  // pool reused by next pass
  }
}

// ---------------------------------------------------------------------------
// MFMA flash attention: R7 version unchanged (110.5 us; defer-max + hs-fold
// + setprio on the proven R12 schedule).
// ---------------------------------------------------------------------------
constexpr int KF0 = 8320;   // u16 idx; SMs = [0,8320) u16 (64x65 f32)
constexpr int VF0 = 16512;  // Kf 8192 u16 (16 KB)
constexpr int PF0 = 24704;  // Vf 8192 u16 (16 KB); Pf 8192 u16 (16 KB)

#define ISSUE_TILE(KT)                                   \
  {                                                      \
    const float* sp_ = shr + (KT);                       \
    const float* mp_ = mkr + (KT);                       \
    pS0 = *(const float4*)(sp_);                         \
    pS1 = *(const float4*)(sp_ + 4);                     \
    pS2 = *(const float4*)(sp_ + 8);                     \
    pS3 = *(const float4*)(sp_ + 12);                    \
    pM0 = *(const float4*)(mp_);                         \
    pM1 = *(const float4*)(mp_ + 4);                     \
    pM2 = *(const float4*)(mp_ + 8);                     \
    pM3 = *(const float4*)(mp_ + 12);                    \
    const u16* h_ = kvsrc_hi + (size_t)(KT) * ktmul;     \
    const u16* l_ = kvsrc_lo + (size_t)(KT) * ktmul;     \
    pK0 = *(const uint4*)(h_);                           \
    pK1 = *(const uint4*)(l_);                           \
    pK2 = *(const uint4*)(h_ + 8);                       \
    pK3 = *(const uint4*)(l_ + 8);                       \
    pK4 = *(const uint4*)(h_ + 16);                      \
    pK5 = *(const uint4*)(l_ + 16);                      \
    pK6 = *(const uint4*)(h_ + 24);                      \
    pK7 = *(const uint4*)(l_ + 24);                      \
  }

// hs folded: store hs*shift (or 1e13 sentinel) so logits are a bare subtract.
#define COMMIT_TILE()                                    \
  {                                                      \
    smd[0 * 65] = (pM0.x != 0.f) ? hs * pS0.x : 1e13f;   \
    smd[1 * 65] = (pM0.y != 0.f) ? hs * pS0.y : 1e13f;   \
    smd[2 * 65] = (pM0.z != 0.f) ? hs * pS0.z : 1e13f;   \
    smd[3 * 65] = (pM0.w != 0.f) ? hs * pS0.w : 1e13f;   \
    smd[4 * 65] = (pM1.x != 0.f) ? hs * pS1.x : 1e13f;   \
    smd[5 * 65] = (pM1.y != 0.f) ? hs * pS1.y : 1e13f;   \
    smd[6 * 65] = (pM1.z != 0.f) ? hs * pS1.z : 1e13f;   \
    smd[7 * 65] = (pM1.w != 0.f) ? hs * pS1.w : 1e13f;   \
    smd[8 * 65] = (pM2.x != 0.f) ? hs * pS2.x : 1e13f;   \
    smd[9 * 65] = (pM2.y != 0.f) ? hs * pS2.y : 1e13f;   \
    smd[10 * 65] = (pM2.z != 0.f) ? hs * pS2.z : 1e13f;  \
    smd[11 * 65] = (pM2.w != 0.f) ? hs * pS2.w : 1e13f;  \
    smd[12 * 65] = (pM3.x != 0.f) ? hs * pS3.x : 1e13f;  \
    smd[13 * 65] = (pM3.y != 0.f) ? hs * pS3.y : 1e13f;  \
    smd[14 * 65] = (pM3.z != 0.f) ? hs * pS3.z : 1e13f;  \
    smd[15 * 65] = (pM3.w != 0.f) ? hs * pS3.w : 1e13f;  \
    *(uint4*)(kvdst + 0) = pK0;                          \
    *(uint4*)(kvdst + 4096) = pK1;                       \
    *(uint4*)(kvdst + 256) = pK2;                        \
    *(uint4*)(kvdst + 4096 + 256) = pK3;                 \
    *(uint4*)(kvdst + 512) = pK4;                        \
    *(uint4*)(kvdst + 4096 + 512) = pK5;                 \
    *(uint4*)(kvdst + 768) = pK6;                        \
    *(uint4*)(kvdst + 4096 + 768) = pK7;                 \
  }

__global__ __launch_bounds__(256, 2) void attn_mfma(
    const u16* __restrict__ Qhi, const u16* __restrict__ Qlo,
    const u16* __restrict__ Khi, const u16* __restrict__ Klo,
    const u16* __restrict__ Vthi, const u16* __restrict__ Vtlo,
    const float* __restrict__ shift, const float* __restrict__ mask,
    u16* __restrict__ Othi, u16* __restrict__ Otlo) {
  const int head = blockIdx.z, b = blockIdx.y, qb = blockIdx.x;
  const int tid = threadIdx.x;
  const int wave = tid >> 6;
  const int wq = wave >> 1, wk = wave & 1;
  const int lane = tid & 63;
  const int l31 = lane & 31, lhi = lane >> 5;

  __shared__ __align__(16) u16 smem[32896];  // 65792 B
  float* SMs = (float*)smem;                 // [64][65] transposed [k][q]
  u16* Pw = smem + PF0 + wave * 2048;        // wave P chunk: hi | lo+1024

  const size_t hb = (size_t)head * Bc + b;
  const int ql = wq * 32 + l31;
  const int qg = qb * 64 + ql;

  // Q B-frags (pre-scaled): n=q, k = t*16 + lhi*8 + j
  bf16x8 qf[2][4];
  {
    const size_t qbase = (hb * Sc + qg) * DHc;
#pragma unroll
    for (int t = 0; t < 4; ++t) {
      qf[0][t] = *(const bf16x8*)(Qhi + qbase + t * 16 + lhi * 8);
      qf[1][t] = *(const bf16x8*)(Qlo + qbase + t * 16 + lhi * 8);
    }
  }
  const float hs = exp2f(-(float)head);

  // SM staging map: thread -> row q = tid>>2, cols (tid&3)*16 .. +15
  const int smq = tid >> 2, smk = (tid & 3) * 16;
  const float* shr = shift + ((size_t)b * Sc + qb * 64 + smq) * Sc + smk;
  const float* mkr = mask + ((size_t)b * Sc + qb * 64 + smq) * Sc + smk;
  float* const smd = SMs + (size_t)smk * 65 + smq;

  // K staging (waves wq==0): 32 keys x 64 dh, half wk
  const int kr = lane >> 1, kh2 = lane & 1;
  const size_t kfix = (hb * Sc + wk * 32 + kr) * 64 + kh2 * 32;
  // V staging (waves wq==1): lane = dh row
  const size_t vfix = (hb * 64 + lane) * 2048 + wk * 32;
  const int vmt = lane >> 5, vdl = lane & 31;

  const u16* const kvsrc_hi = (wq == 0) ? (Khi + kfix) : (Vthi + vfix);
  const u16* const kvsrc_lo = (wq == 0) ? (Klo + kfix) : (Vtlo + vfix);
  const int ktmul = (wq == 0) ? 64 : 1;
  u16* const kvdst = (wq == 0)
                         ? &smem[KF0 + (wk * 4 + kh2 * 2) * 512 + kr * 8]
                         : &smem[VF0 + (wk * 4 + vmt * 2) * 512 + vdl * 8];

  float m_run = -INFINITY, l_run = 0.f;
  f32x16 o0, o1;
#pragma unroll
  for (int i = 0; i < 16; ++i) {
    o0[i] = 0.f;
    o1[i] = 0.f;
  }

  // T14 prefetch registers (named; never indexed -> stay in VGPRs)
  float4 pS0, pS1, pS2, pS3, pM0, pM1, pM2, pM3;
  uint4 pK0, pK1, pK2, pK3, pK4, pK5, pK6, pK7;

  ISSUE_TILE(0);
  for (int it = 0; it < 32; ++it) {
    COMMIT_TILE();  // regs -> LDS
    __syncthreads();
    if (it < 31) ISSUE_TILE(it * 64 + 64);  // overlap next HBM fetch w/ compute

    // ---- S^T = K·Q^T (m=key32, n=q32): Khi*Qhi + Khi*Qlo + Klo*Qhi
    f32x16 s;
#pragma unroll
    for (int i = 0; i < 16; ++i) s[i] = 0.f;
    __builtin_amdgcn_s_setprio(1);
#pragma unroll
    for (int t = 0; t < 4; ++t) {
      const bf16x8 kh = *(const bf16x8*)&smem[KF0 +
          (((0 * 2 + wk) * 4 + t) * 64 + lane) * 8];
      const bf16x8 kl = *(const bf16x8*)&smem[KF0 +
          (((1 * 2 + wk) * 4 + t) * 64 + lane) * 8];
      s = MFMA32(kh, qf[0][t], s, 0, 0, 0);
      s = MFMA32(kh, qf[1][t], s, 0, 0, 0);
      s = MFMA32(kl, qf[0][t], s, 0, 0, 0);
    }
    __builtin_amdgcn_s_setprio(0);

    // ---- logits from SMs (hs pre-folded) + online softmax w/ defer-max
    float p[16];
    float kmax = -INFINITY;
#pragma unroll
    for (int c = 0; c < 4; ++c) {
#pragma unroll
      for (int e = 0; e < 4; ++e) {
        const int kl_ = wk * 32 + c * 8 + lhi * 4 + e;
        const float lg = s[4 * c + e] - SMs[(size_t)kl_ * 65 + ql];
        p[4 * c + e] = lg;
        kmax = fmaxf(kmax, lg);
      }
    }
    kmax = fmaxf(kmax, __shfl_xor(kmax, 32, 64));

    // T13 defer-max: only rescale when the running max grew by > 8.
    if (!__all(kmax <= m_run + 8.f)) {
      const float mnew = fmaxf(m_run, kmax);
      const float alpha = __expf(m_run - mnew);
      l_run *= alpha;
      m_run = mnew;
#pragma unroll
      for (int i = 0; i < 16; ++i) {
        o0[i] *= alpha;
        o1[i] *= alpha;
      }
    }
    float rsum = 0.f;
#pragma unroll
    for (int r = 0; r < 16; ++r) {
      p[r] = __expf(p[r] - m_run);
      rsum += p[r];
    }
    rsum += __shfl_xor(rsum, 32, 64);
    l_run += rsum;

    // ---- P -> own LDS chunk (same-wave DS ordering; no barrier needed)
#pragma unroll
    for (int c = 0; c < 4; ++c) {
      const uint2 s01 = splitpack2(p[4 * c + 0], p[4 * c + 1]);
      const uint2 s23 = splitpack2(p[4 * c + 2], p[4 * c + 3]);
      const int t = c >> 1, lh = c & 1;
      const int bi = (t * 64 + lh * 32 + l31) * 8 + lhi * 4;
      *(uint2*)&Pw[bi] = uint2{s01.x, s23.x};
      *(uint2*)&Pw[1024 + bi] = uint2{s01.y, s23.y};
    }

    // ---- O^T += V^T · P^T
    __builtin_amdgcn_s_setprio(1);
#pragma unroll
    for (int t = 0; t < 2; ++t) {
      const bf16x8 ph = *(const bf16x8*)&Pw[(t * 64 + lane) * 8];
      const bf16x8 pl_ = *(const bf16x8*)&Pw[1024 + (t * 64 + lane) * 8];
      bf16x8 vh = *(const bf16x8*)&smem[VF0 +
          ((((0 * 2 + wk) * 2 + 0) * 2 + t) * 64 + lane) * 8];
      bf16x8 vl = *(const bf16x8*)&smem[VF0 +
          ((((1 * 2 + wk) * 2 + 0) * 2 + t) * 64 + lane) * 8];
      o0 = MFMA32(vh, ph, o0, 0, 0, 0);
      o0 = MFMA32(vh, pl_, o0, 0, 0, 0);
      o0 = MFMA32(vl, ph, o0, 0, 0, 0);
      vh = *(const bf16x8*)&smem[VF0 +
          ((((0 * 2 + wk) * 2 + 1) * 2 + t) * 64 + lane) * 8];
      vl = *(const bf16x8*)&smem[VF0 +
          ((((1 * 2 + wk) * 2 + 1) * 2 + t) * 64 + lane) * 8];
      o1 = MFMA32(vh, ph, o1, 0, 0, 0);
      o1 = MFMA32(vh, pl_, o1, 0, 0, 0);
      o1 = MFMA32(vl, ph, o1, 0, 0, 0);
    }
    __builtin_amdgcn_s_setprio(0);
    __syncthreads();
  }

  // ---- merge wk=0/1 (same wq) through LDS (overlays Kf/Vf, dead now)
  float* mL = (float*)(smem + KF0);  // 64
  float* lL = mL + 64;               // 64
  float* Om = lL + 64;               // [2][64][33]
  if (wk == 1) {
    if (lhi == 0) {
      mL[wq * 32 + l31] = m_run;
      lL[wq * 32 + l31] = l_run;
    }
#pragma unroll
    for (int mt = 0; mt < 2; ++mt)
#pragma unroll
      for (int r = 0; r < 16; ++r) {
        const int row = mt * 32 + (r & 3) + 8 * (r >> 2) + 4 * lhi;
        Om[(wq * 64 + row) * 33 + l31] = (mt ? o1[r] : o0[r]);
      }
  }
  __syncthreads();
  if (wk == 0) {
    const float m1 = mL[wq * 32 + l31];
    const float l1v = lL[wq * 32 + l31];
    const float mst = fmaxf(m_run, m1);
    const float a0 = __expf(m_run - mst), a1 = __expf(m1 - mst);
    const float inv = 1.f / (a0 * l_run + a1 * l1v);
    const int tok = b * 2048 + qg;
#pragma unroll
    for (int mt = 0; mt < 2; ++mt)
#pragma unroll
      for (int r = 0; r < 16; ++r) {
        const int row = mt * 32 + (r & 3) + 8 * (r >> 2) + 4 * lhi;
        const float val = (a0 * (mt ? o1[r] : o0[r]) +
                           a1 * Om[(wq * 64 + row) * 33 + l31]) *
                          inv;
        const int d = head * 64 + row;
        u16 hi, lo;
        split1(val, hi, lo);
        const size_t idx = ((size_t)(d >> 3) * 4096 + tok) * 8 + (d & 7);
        Othi[idx] = hi;
        Otlo[idx] = lo;
      }
  }
}

// ---------------------------------------------------------------------------
// GEMM2 (MFMA): out = o @ Wo^T + bo. EXACT R5/R7 reg-staged version (R8's
// global_load_lds variant regressed: 32-line/instr gather + lost prefetch).
// ---------------------------------------------------------------------------
#define G2_ISSUE(K0)                                        \
  {                                                         \
    g2ah = *(const uint4*)(srcAh + (size_t)(K0) * 4096);    \
    g2al = *(const uint4*)(srcAl + (size_t)(K0) * 4096);    \
    g2bh = *(const uint4*)(srcBh + (K0));                   \
    g2bl = *(const uint4*)(srcBl + (K0));                   \
  }
#define G2_COMMIT()                                         \
  {                                                         \
    *(uint4*)dAh = g2ah;                                    \
    *(uint4*)dAl = g2al;                                    \
    *(uint4*)dBh = g2bh;                                    \
    *(uint4*)dBl = g2bl;                                    \
  }

__global__ __launch_bounds__(256, 2) void gemm2_mfma(
    const u16* __restrict__ Othi, const u16* __restrict__ Otlo,
    const u16* __restrict__ Wohi, const u16* __restrict__ Wolo,
    const float* __restrict__ bo, float* __restrict__ out) {
  __shared__ __align__(16) u16 Af[2][2][2][64][8];  // 8 KB
  __shared__ __align__(16) u16 Bf[2][2][2][64][8];  // 8 KB
  const int tid = threadIdx.x;
  const int wave = tid >> 6, lane = tid & 63, l31 = lane & 31, lhi = lane >> 5;
  const int wm = wave >> 1, wn = wave & 1;
  const int m0 = blockIdx.y * 64, n0 = blockIdx.x * 64;

  const int cA = tid >> 6, tokA = tid & 63;
  u16* const dAh = &Af[0][tokA >> 5][cA >> 1][(cA & 1) * 32 + (tokA & 31)][0];
  u16* const dAl = &Af[1][tokA >> 5][cA >> 1][(cA & 1) * 32 + (tokA & 31)][0];
  const u16* const srcAh = Othi + ((size_t)cA * 4096 + m0 + tokA) * 8;
  const u16* const srcAl = Otlo + ((size_t)cA * 4096 + m0 + tokA) * 8;
  const int nB = tid >> 2, cB = tid & 3;
  u16* const dBh = &Bf[0][nB >> 5][cB >> 1][(cB & 1) * 32 + (nB & 31)][0];
  u16* const dBl = &Bf[1][nB >> 5][cB >> 1][(cB & 1) * 32 + (nB & 31)][0];
  const u16* const srcBh = Wohi + (size_t)(n0 + nB) * 512 + cB * 8;
  const u16* const srcBl = Wolo + (size_t)(n0 + nB) * 512 + cB * 8;

  f32x16 acc;
#pragma unroll
  for (int r = 0; r < 16; ++r) acc[r] = 0.f;

  uint4 g2ah, g2al, g2bh, g2bl;
  G2_ISSUE(0);
  for (int k0 = 0; k0 < 512; k0 += 32) {
    G2_COMMIT();
    __syncthreads();
    if (k0 < 480) G2_ISSUE(k0 + 32);
#pragma unroll
    for (int t = 0; t < 2; ++t) {
      const bf16x8 ah = *(const bf16x8*)&Af[0][wm][t][lane][0];
      const bf16x8 al = *(const bf16x8*)&Af[1][wm][t][lane][0];
      const bf16x8 bh = *(const bf16x8*)&Bf[0][wn][t][lane][0];
      const bf16x8 bl = *(const bf16x8*)&Bf[1][wn][t][lane][0];
      acc = MFMA32(ah, bh, acc, 0, 0, 0);
      acc = MFMA32(ah, bl, acc, 0, 0, 0);
      acc = MFMA32(al, bh, acc, 0, 0, 0);
    }
    __syncthreads();
  }

  const int n = n0 + wn * 32 + l31;
  const float bn = bo[n];
#pragma unroll
  for (int r = 0; r < 16; ++r) {
    const int m = m0 + wm * 32 + (r & 3) + 8 * (r >> 2) + 4 * lhi;
    out[(size_t)m * 512 + n] = acc[r] + bn;
  }
}

// ---------------------------------------------------------------------------
extern "C" void kernel_launch(void* const* d_in, const int* in_sizes, int n_in,
                              void* d_out, int out_size, void* d_ws,
                              size_t ws_size, hipStream_t stream) {
  const float* x = (const float*)d_in[0];
  const float* shift = (const float*)d_in[1];
  const float* mask = (const float*)d_in[2];
  const float* W = (const float*)d_in[3];
  const float* b = (const float*)d_in[4];
  const float* Wo = (const float*)d_in[5];
  const float* bo = (const float*)d_in[6];
  float* out = (float*)d_out;

  // ws (32 MiB): [0,6P) Q/K/V hi+lo planes (dead after attn; Wo planes reuse
  // the head of this region), [6P,8P) X planes (phase 1) then Ot planes.
  // W planes live in d_out until gemm2.
  const size_t P = (size_t)Hc * Bc * Sc * DHc;  // 2,097,152
  u16* ws0 = (u16*)d_ws;
  u16* Qhi = ws0;
  u16* Qlo = ws0 + P;
  u16* Khi = ws0 + 2 * P;
  u16* Klo = ws0 + 3 * P;
  u16* Vthi = ws0 + 4 * P;
  u16* Vtlo = ws0 + 5 * P;
  u16* Othi = ws0 + 6 * P;
  u16* Otlo = ws0 + 7 * P;
  u16* Xhi = ws0 + 6 * P;  // aliases Ot region (dead until attn)
  u16* Xlo = ws0 + 7 * P;
  u16* Whi = (u16*)out;  // d_out as scratch until gemm2
  u16* Wlo = (u16*)out + 786432;
  u16* Wohi = ws0;                // aliases Q region (dead after attn)
  u16* Wolo = ws0 + 262144;

  // 0) pre-split x and W to bf16 hi/lo planes
  presplit_xw<<<dim3(1408), 256, 0, stream>>>(x, W, Xhi, Xlo, Whi, Wlo);

  // 1) QKV projection (MFMA, 128x128 tile; Q pre-scaled)
  gemm1_mfma<<<dim3(NQKV / 128, (Bc * Sc) / 128), 256, 0, stream>>>(
      Xhi, Xlo, Whi, Wlo, b, Qhi, Qlo, Khi, Klo, Vthi, Vtlo);

  // 2) MFMA flash attention (R7) -> Ot planes
  attn_mfma<<<dim3(Sc / 64, Bc, Hc), 256, 0, stream>>>(
      Qhi, Qlo, Khi, Klo, Vthi, Vtlo, shift, mask, Othi, Otlo);

  // 2b) pre-split Wo into the now-dead Q region
  presplit_wo<<<dim3(128), 256, 0, stream>>>(Wo, Wohi, Wolo);

  // 3) output projection (MFMA, reg-staged) -> out
  gemm2_mfma<<<dim3(Dc / 64, (Bc * Sc) / 64), 256, 0, stream>>>(
      Othi, Otlo, Wohi, Wolo, bo, out);
}

// Round 10
// 249.203 us; speedup vs baseline: 1.0427x; 1.0207x over previous
//
#include <hip/hip_runtime.h>
#include <math.h>

// Problem constants (fixed by reference)
constexpr int Bc = 2, Sc = 2048, Dc = 512, Hc = 8, DHc = 64;
constexpr int NQKV = 3 * Dc;  // 1536

typedef unsigned short u16;
typedef unsigned int u32;
typedef __attribute__((ext_vector_type(8))) __bf16 bf16x8;
typedef __attribute__((ext_vector_type(16))) float f32x16;

#define MFMA32 __builtin_amdgcn_mfma_f32_32x32x16_bf16

// Truncation hi/lo split of two floats, packed: ret.x = (hi(b)<<16)|hi(a),
// ret.y = lo-pair. hi = truncate-to-bf16; lo = bf16(residual).
__device__ inline uint2 splitpack2(float a, float b) {
  u32 ua = __float_as_uint(a), ub = __float_as_uint(b);
  u32 hi = (ub & 0xFFFF0000u) | (ua >> 16);
  float ra = a - __uint_as_float(ua & 0xFFFF0000u);
  float rb = b - __uint_as_float(ub & 0xFFFF0000u);
  u32 lo = (__float_as_uint(rb) & 0xFFFF0000u) | (__float_as_uint(ra) >> 16);
  return uint2{hi, lo};
}
__device__ inline void split1(float v, u16& hi, u16& lo) {
  u32 u = __float_as_uint(v);
  hi = (u16)(u >> 16);
  float r = v - __uint_as_float(u & 0xFFFF0000u);
  lo = (u16)(__float_as_uint(r) >> 16);
}

// ---------------------------------------------------------------------------
// Pre-split: x -> Xhi/Xlo planes (ws, dead-Ot region), W -> Whi/Wlo (d_out
// used as scratch until gemm2).
// ---------------------------------------------------------------------------
__global__ __launch_bounds__(256) void presplit_xw(
    const float* __restrict__ x, const float* __restrict__ W,
    u16* __restrict__ Xhi, u16* __restrict__ Xlo, u16* __restrict__ Whi,
    u16* __restrict__ Wlo) {
  const u32 g = blockIdx.x * 256 + threadIdx.x;  // 8-elem group
  const float* src;
  u16 *dh, *dl;
  if (g < 262144u) {  // x: 2,097,152 elems
    src = x + (size_t)g * 8;
    dh = Xhi + (size_t)g * 8;
    dl = Xlo + (size_t)g * 8;
  } else {  // W: 786,432 elems
    const u32 gw = g - 262144u;
    src = W + (size_t)gw * 8;
    dh = Whi + (size_t)gw * 8;
    dl = Wlo + (size_t)gw * 8;
  }
  const float4 v0 = *(const float4*)src;
  const float4 v1 = *(const float4*)(src + 4);
  const uint2 p0 = splitpack2(v0.x, v0.y), p1 = splitpack2(v0.z, v0.w);
  const uint2 p2 = splitpack2(v1.x, v1.y), p3 = splitpack2(v1.z, v1.w);
  *(uint4*)dh = uint4{p0.x, p1.x, p2.x, p3.x};
  *(uint4*)dl = uint4{p0.y, p1.y, p2.y, p3.y};
}

// ---------------------------------------------------------------------------
// Pre-split Wo (runs AFTER attn; Q/K/V ws region is dead then).
// ---------------------------------------------------------------------------
__global__ __launch_bounds__(256) void presplit_wo(const float* __restrict__ Wo,
                                                   u16* __restrict__ Wohi,
                                                   u16* __restrict__ Wolo) {
  const u32 g = blockIdx.x * 256 + threadIdx.x;  // 8-elem group, 32768 total
  const float* src = Wo + (size_t)g * 8;
  const float4 v0 = *(const float4*)src;
  const float4 v1 = *(const float4*)(src + 4);
  const uint2 p0 = splitpack2(v0.x, v0.y), p1 = splitpack2(v0.z, v0.w);
  const uint2 p2 = splitpack2(v1.x, v1.y), p3 = splitpack2(v1.z, v1.w);
  *(uint4*)(Wohi + (size_t)g * 8) = uint4{p0.x, p1.x, p2.x, p3.x};
  *(uint4*)(Wolo + (size_t)g * 8) = uint4{p0.y, p1.y, p2.y, p3.y};
}

// ---------------------------------------------------------------------------
// GEMM1 (MFMA): qkv = x @ W^T + b from PRE-SPLIT bf16 planes. EXACT R5/R7
// version (best-measured rest config): BK=32, tile 128x64, 3 blocks/CU.
// ---------------------------------------------------------------------------
#define G1_ISSUE(K0)                          \
  {                                           \
    a0h = *(const uint4*)(srcA0h + (K0));     \
    a0l = *(const uint4*)(srcA0l + (K0));     \
    a1h = *(const uint4*)(srcA1h + (K0));     \
    a1l = *(const uint4*)(srcA1l + (K0));     \
    b0h = *(const uint4*)(srcBh + (K0));      \
    b0l = *(const uint4*)(srcBl + (K0));      \
  }
#define G1_COMMIT()                           \
  {                                           \
    *(uint4*)dA0h = a0h;                      \
    *(uint4*)dA0l = a0l;                      \
    *(uint4*)dA1h = a1h;                      \
    *(uint4*)dA1l = a1l;                      \
    *(uint4*)dBh = b0h;                       \
    *(uint4*)dBl = b0l;                       \
  }

__global__ __launch_bounds__(256, 3) void gemm1_mfma(
    const u16* __restrict__ Xhi, const u16* __restrict__ Xlo,
    const u16* __restrict__ Whi, const u16* __restrict__ Wlo,
    const float* __restrict__ bias, u16* __restrict__ Qhi,
    u16* __restrict__ Qlo, u16* __restrict__ Khi, u16* __restrict__ Klo,
    u16* __restrict__ Vthi, u16* __restrict__ Vtlo) {
  __shared__ __align__(16) u16 pool[18432];  // 36 KB
  const int tid = threadIdx.x;
  const int wave = tid >> 6, lane = tid & 63, l31 = lane & 31, lhi = lane >> 5;
  const int wm = wave >> 1, wn = wave & 1;
  const int m0 = blockIdx.y * 128, n0 = blockIdx.x * 64;

  const int mA = tid >> 2, kgA = tid & 3;
  const int rowA = (kgA & 1) * 32 + (mA & 31);
  u16* const dA0h = &pool[(((mA >> 5) * 2 + (kgA >> 1)) * 64 + rowA) * 8];
  u16* const dA0l = dA0h + 4096;
  u16* const dA1h =
      &pool[(((2 + (mA >> 5)) * 2 + (kgA >> 1)) * 64 + rowA) * 8];
  u16* const dA1l = dA1h + 4096;
  u16* const dBh = &pool[8192 + (((mA >> 5) * 2 + (kgA >> 1)) * 64 + rowA) * 8];
  u16* const dBl = dBh + 2048;
  const u16* const srcA0h = Xhi + (size_t)(m0 + mA) * 512 + kgA * 8;
  const u16* const srcA0l = Xlo + (size_t)(m0 + mA) * 512 + kgA * 8;
  const u16* const srcA1h = srcA0h + 64 * 512;
  const u16* const srcA1l = srcA0l + 64 * 512;
  const u16* const srcBh = Whi + (size_t)(n0 + mA) * 512 + kgA * 8;
  const u16* const srcBl = Wlo + (size_t)(n0 + mA) * 512 + kgA * 8;

  f32x16 acc[2];
#pragma unroll
  for (int r = 0; r < 16; ++r) {
    acc[0][r] = 0.f;
    acc[1][r] = 0.f;
  }

  uint4 a0h, a0l, a1h, a1l, b0h, b0l;
  G1_ISSUE(0);
  for (int k0 = 0; k0 < 512; k0 += 32) {
    G1_COMMIT();
    __syncthreads();
    if (k0 < 480) G1_ISSUE(k0 + 32);
#pragma unroll
    for (int t = 0; t < 2; ++t) {
      const bf16x8 bh =
          *(const bf16x8*)&pool[8192 + (((0 * 2 + wn) * 2 + t) * 64 + lane) * 8];
      const bf16x8 bl =
          *(const bf16x8*)&pool[8192 + (((1 * 2 + wn) * 2 + t) * 64 + lane) * 8];
#pragma unroll
      for (int ti = 0; ti < 2; ++ti) {
        const bf16x8 ah =
            *(const bf16x8*)&pool[(((0 * 4 + wm * 2 + ti) * 2 + t) * 64 + lane) * 8];
        const bf16x8 al =
            *(const bf16x8*)&pool[(((1 * 4 + wm * 2 + ti) * 2 + t) * 64 + lane) * 8];
        acc[ti] = MFMA32(ah, bh, acc[ti], 0, 0, 0);
        acc[ti] = MFMA32(ah, bl, acc[ti], 0, 0, 0);
        acc[ti] = MFMA32(al, bh, acc[ti], 0, 0, 0);
      }
    }
    __syncthreads();
  }

  // ---- epilogue: LDS-staged coalesced stores ----
  const int n = n0 + wn * 32 + l31;
  const float bn = bias[n];
  const int h = n0 / 192;
  const int t3 = (n0 % 192) / 64;
  const int dh = wn * 32 + l31;
  const int batch = m0 >> 11;
  const int s0 = m0 & 2047;
  const int hbq = h * 2 + batch;

#pragma unroll
  for (int ti = 0; ti < 2; ++ti)
#pragma unroll
    for (int r = 0; r < 16; ++r) {
      const int tl = wm * 64 + ti * 32 + (r & 3) + 8 * (r >> 2) + 4 * lhi;
      float val = acc[ti][r] + bn;
      if (t3 == 0) val *= 0.125f;  // fold logit scale into Q
      u16 hi, lo;
      split1(val, hi, lo);
      pool[tl * 72 + dh] = hi;
      pool[9216 + tl * 72 + dh] = lo;
    }
  __syncthreads();

  u16 *d0, *d1;
  if (t3 == 0) {
    d0 = Qhi;
    d1 = Qlo;
  } else if (t3 == 1) {
    d0 = Khi;
    d1 = Klo;
  } else {
    d0 = Vthi;
    d1 = Vtlo;
  }

  if (t3 != 2) {
    const size_t base = ((size_t)hbq * 2048 + s0) * 64;
#pragma unroll
    for (int p = 0; p < 2; ++p) {
      u16* dst = (p ? d1 : d0) + base;
#pragma unroll
      for (int j = 0; j < 4; ++j) {
        const int g = tid * 32 + j * 8;
        const int token = g >> 6, dh8 = g & 63;
        *(uint4*)(dst + g) = *(const uint4*)&pool[p * 9216 + token * 72 + dh8];
      }
    }
  } else {
    const int d = tid >> 2, tp = (tid & 3) * 32;
#pragma unroll
    for (int p = 0; p < 2; ++p) {
      u16* dst = (p ? d1 : d0) + ((size_t)hbq * 64 + d) * 2048 + s0 + tp;
      u32 w[16];
#pragma unroll
      for (int j = 0; j < 16; ++j) {
        const u16 a = pool[p * 9216 + (tp + 2 * j) * 72 + d];
        const u16 b2 = pool[p * 9216 + (tp + 2 * j + 1) * 72 + d];
        w[j] = (u32)a | ((u32)b2 << 16);
      }
#pragma unroll
      for (int j = 0; j < 4; ++j)
        *(uint4*)(dst + j * 8) =
            uint4{w[4 * j], w[4 * j + 1], w[4 * j + 2], w[4 * j + 3]};
    }
  }
}

// ---------------------------------------------------------------------------
// MFMA flash attention R18: R7 schedule (defer-max + hs-fold + setprio on the
// proven R12 loop) with ONE change: the SM buffer is now [q][k] with row
// stride 76 floats (16B-aligned rows; 76 mod 32 = 12 -> conflict-light b128
// bank walk). SM commit: 4 float4 stores/thread (was 16 scalar b32);
// logits: 4 float4 loads/lane (was 16 scalar b32). Cuts ~96 LDS-pipe
// cycles + addressing VALU off the serial chain per wave-iter.
// ---------------------------------------------------------------------------
constexpr int SMSTRIDE = 76;  // floats per q-row
constexpr int KF0 = 9728;     // u16 idx; SMs = [0,9728) u16 (64x76 f32)
constexpr int VF0 = 17920;    // Kf 8192 u16 (16 KB)
constexpr int PF0 = 26112;    // Vf 8192 u16 (16 KB); Pf 8192 u16 (16 KB)

#define ISSUE_TILE(KT)                                   \
  {                                                      \
    const float* sp_ = shr + (KT);                       \
    const float* mp_ = mkr + (KT);                       \
    pS0 = *(const float4*)(sp_);                         \
    pS1 = *(const float4*)(sp_ + 4);                     \
    pS2 = *(const float4*)(sp_ + 8);                     \
    pS3 = *(const float4*)(sp_ + 12);                    \
    pM0 = *(const float4*)(mp_);                         \
    pM1 = *(const float4*)(mp_ + 4);                     \
    pM2 = *(const float4*)(mp_ + 8);                     \
    pM3 = *(const float4*)(mp_ + 12);                    \
    const u16* h_ = kvsrc_hi + (size_t)(KT) * ktmul;     \
    const u16* l_ = kvsrc_lo + (size_t)(KT) * ktmul;     \
    pK0 = *(const uint4*)(h_);                           \
    pK1 = *(const uint4*)(l_);                           \
    pK2 = *(const uint4*)(h_ + 8);                       \
    pK3 = *(const uint4*)(l_ + 8);                       \
    pK4 = *(const uint4*)(h_ + 16);                      \
    pK5 = *(const uint4*)(l_ + 16);                      \
    pK6 = *(const uint4*)(h_ + 24);                      \
    pK7 = *(const uint4*)(l_ + 24);                      \
  }

// hs folded; SM rows are k-contiguous -> 4 vector stores.
#define COMMIT_TILE()                                        \
  {                                                          \
    float4 f0, f1, f2, f3;                                   \
    f0.x = (pM0.x != 0.f) ? hs * pS0.x : 1e13f;              \
    f0.y = (pM0.y != 0.f) ? hs * pS0.y : 1e13f;              \
    f0.z = (pM0.z != 0.f) ? hs * pS0.z : 1e13f;              \
    f0.w = (pM0.w != 0.f) ? hs * pS0.w : 1e13f;              \
    f1.x = (pM1.x != 0.f) ? hs * pS1.x : 1e13f;              \
    f1.y = (pM1.y != 0.f) ? hs * pS1.y : 1e13f;              \
    f1.z = (pM1.z != 0.f) ? hs * pS1.z : 1e13f;              \
    f1.w = (pM1.w != 0.f) ? hs * pS1.w : 1e13f;              \
    f2.x = (pM2.x != 0.f) ? hs * pS2.x : 1e13f;              \
    f2.y = (pM2.y != 0.f) ? hs * pS2.y : 1e13f;              \
    f2.z = (pM2.z != 0.f) ? hs * pS2.z : 1e13f;              \
    f2.w = (pM2.w != 0.f) ? hs * pS2.w : 1e13f;              \
    f3.x = (pM3.x != 0.f) ? hs * pS3.x : 1e13f;              \
    f3.y = (pM3.y != 0.f) ? hs * pS3.y : 1e13f;              \
    f3.z = (pM3.z != 0.f) ? hs * pS3.z : 1e13f;              \
    f3.w = (pM3.w != 0.f) ? hs * pS3.w : 1e13f;              \
    *(float4*)(smd + 0) = f0;                                \
    *(float4*)(smd + 4) = f1;                                \
    *(float4*)(smd + 8) = f2;                                \
    *(float4*)(smd + 12) = f3;                               \
    *(uint4*)(kvdst + 0) = pK0;                              \
    *(uint4*)(kvdst + 4096) = pK1;                           \
    *(uint4*)(kvdst + 256) = pK2;                            \
    *(uint4*)(kvdst + 4096 + 256) = pK3;                     \
    *(uint4*)(kvdst + 512) = pK4;                            \
    *(uint4*)(kvdst + 4096 + 512) = pK5;                     \
    *(uint4*)(kvdst + 768) = pK6;                            \
    *(uint4*)(kvdst + 4096 + 768) = pK7;                     \
  }

__global__ __launch_bounds__(256, 2) void attn_mfma(
    const u16* __restrict__ Qhi, const u16* __restrict__ Qlo,
    const u16* __restrict__ Khi, const u16* __restrict__ Klo,
    const u16* __restrict__ Vthi, const u16* __restrict__ Vtlo,
    const float* __restrict__ shift, const float* __restrict__ mask,
    u16* __restrict__ Othi, u16* __restrict__ Otlo) {
  const int head = blockIdx.z, b = blockIdx.y, qb = blockIdx.x;
  const int tid = threadIdx.x;
  const int wave = tid >> 6;
  const int wq = wave >> 1, wk = wave & 1;
  const int lane = tid & 63;
  const int l31 = lane & 31, lhi = lane >> 5;

  __shared__ __align__(16) u16 smem[34304];  // 68608 B -> 2 blocks/CU
  float* SMs = (float*)smem;                 // [64 q][76] (k-contiguous rows)
  u16* Pw = smem + PF0 + wave * 2048;        // wave P chunk: hi | lo+1024

  const size_t hb = (size_t)head * Bc + b;
  const int ql = wq * 32 + l31;
  const int qg = qb * 64 + ql;

  // Q B-frags (pre-scaled): n=q, k = t*16 + lhi*8 + j
  bf16x8 qf[2][4];
  {
    const size_t qbase = (hb * Sc + qg) * DHc;
#pragma unroll
    for (int t = 0; t < 4; ++t) {
      qf[0][t] = *(const bf16x8*)(Qhi + qbase + t * 16 + lhi * 8);
      qf[1][t] = *(const bf16x8*)(Qlo + qbase + t * 16 + lhi * 8);
    }
  }
  const float hs = exp2f(-(float)head);

  // SM staging map: thread -> row q = tid>>2, cols (tid&3)*16 .. +15
  const int smq = tid >> 2, smk = (tid & 3) * 16;
  const float* shr = shift + ((size_t)b * Sc + qb * 64 + smq) * Sc + smk;
  const float* mkr = mask + ((size_t)b * Sc + qb * 64 + smq) * Sc + smk;
  float* const smd = SMs + (size_t)smq * SMSTRIDE + smk;

  // K staging (waves wq==0): 32 keys x 64 dh, half wk
  const int kr = lane >> 1, kh2 = lane & 1;
  const size_t kfix = (hb * Sc + wk * 32 + kr) * 64 + kh2 * 32;
  // V staging (waves wq==1): lane = dh row
  const size_t vfix = (hb * 64 + lane) * 2048 + wk * 32;
  const int vmt = lane >> 5, vdl = lane & 31;

  const u16* const kvsrc_hi = (wq == 0) ? (Khi + kfix) : (Vthi + vfix);
  const u16* const kvsrc_lo = (wq == 0) ? (Klo + kfix) : (Vtlo + vfix);
  const int ktmul = (wq == 0) ? 64 : 1;
  u16* const kvdst = (wq == 0)
                         ? &smem[KF0 + (wk * 4 + kh2 * 2) * 512 + kr * 8]
                         : &smem[VF0 + (wk * 4 + vmt * 2) * 512 + vdl * 8];

  float m_run = -INFINITY, l_run = 0.f;
  f32x16 o0, o1;
#pragma unroll
  for (int i = 0; i < 16; ++i) {
    o0[i] = 0.f;
    o1[i] = 0.f;
  }

  // T14 prefetch registers (named; never indexed -> stay in VGPRs)
  float4 pS0, pS1, pS2, pS3, pM0, pM1, pM2, pM3;
  uint4 pK0, pK1, pK2, pK3, pK4, pK5, pK6, pK7;

  ISSUE_TILE(0);
  for (int it = 0; it < 32; ++it) {
    COMMIT_TILE();  // regs -> LDS
    __syncthreads();
    if (it < 31) ISSUE_TILE(it * 64 + 64);  // overlap next HBM fetch w/ compute

    // ---- S^T = K·Q^T (m=key32, n=q32): Khi*Qhi + Khi*Qlo + Klo*Qhi
    f32x16 s;
#pragma unroll
    for (int i = 0; i < 16; ++i) s[i] = 0.f;
    __builtin_amdgcn_s_setprio(1);
#pragma unroll
    for (int t = 0; t < 4; ++t) {
      const bf16x8 kh = *(const bf16x8*)&smem[KF0 +
          (((0 * 2 + wk) * 4 + t) * 64 + lane) * 8];
      const bf16x8 kl = *(const bf16x8*)&smem[KF0 +
          (((1 * 2 + wk) * 4 + t) * 64 + lane) * 8];
      s = MFMA32(kh, qf[0][t], s, 0, 0, 0);
      s = MFMA32(kh, qf[1][t], s, 0, 0, 0);
      s = MFMA32(kl, qf[0][t], s, 0, 0, 0);
    }
    __builtin_amdgcn_s_setprio(0);

    // ---- logits from SMs ([q][k] rows -> 4 vector loads) + defer-max
    float p[16];
    float kmax = -INFINITY;
#pragma unroll
    for (int c = 0; c < 4; ++c) {
      const float4 sm4 = *(const float4*)&SMs[(size_t)ql * SMSTRIDE +
                                              wk * 32 + c * 8 + lhi * 4];
      p[4 * c + 0] = s[4 * c + 0] - sm4.x;
      p[4 * c + 1] = s[4 * c + 1] - sm4.y;
      p[4 * c + 2] = s[4 * c + 2] - sm4.z;
      p[4 * c + 3] = s[4 * c + 3] - sm4.w;
      kmax = fmaxf(kmax, fmaxf(fmaxf(p[4 * c + 0], p[4 * c + 1]),
                               fmaxf(p[4 * c + 2], p[4 * c + 3])));
    }
    kmax = fmaxf(kmax, __shfl_xor(kmax, 32, 64));

    // T13 defer-max: only rescale when the running max grew by > 8.
    if (!__all(kmax <= m_run + 8.f)) {
      const float mnew = fmaxf(m_run, kmax);
      const float alpha = __expf(m_run - mnew);
      l_run *= alpha;
      m_run = mnew;
#pragma unroll
      for (int i = 0; i < 16; ++i) {
        o0[i] *= alpha;
        o1[i] *= alpha;
      }
    }
    float rsum = 0.f;
#pragma unroll
    for (int r = 0; r < 16; ++r) {
      p[r] = __expf(p[r] - m_run);
      rsum += p[r];
    }
    rsum += __shfl_xor(rsum, 32, 64);
    l_run += rsum;

    // ---- P -> own LDS chunk (same-wave DS ordering; no barrier needed)
#pragma unroll
    for (int c = 0; c < 4; ++c) {
      const uint2 s01 = splitpack2(p[4 * c + 0], p[4 * c + 1]);
      const uint2 s23 = splitpack2(p[4 * c + 2], p[4 * c + 3]);
      const int t = c >> 1, lh = c & 1;
      const int bi = (t * 64 + lh * 32 + l31) * 8 + lhi * 4;
      *(uint2*)&Pw[bi] = uint2{s01.x, s23.x};
      *(uint2*)&Pw[1024 + bi] = uint2{s01.y, s23.y};
    }

    // ---- O^T += V^T · P^T
    __builtin_amdgcn_s_setprio(1);
#pragma unroll
    for (int t = 0; t < 2; ++t) {
      const bf16x8 ph = *(const bf16x8*)&Pw[(t * 64 + lane) * 8];
      const bf16x8 pl_ = *(const bf16x8*)&Pw[1024 + (t * 64 + lane) * 8];
      bf16x8 vh = *(const bf16x8*)&smem[VF0 +
          ((((0 * 2 + wk) * 2 + 0) * 2 + t) * 64 + lane) * 8];
      bf16x8 vl = *(const bf16x8*)&smem[VF0 +
          ((((1 * 2 + wk) * 2 + 0) * 2 + t) * 64 + lane) * 8];
      o0 = MFMA32(vh, ph, o0, 0, 0, 0);
      o0 = MFMA32(vh, pl_, o0, 0, 0, 0);
      o0 = MFMA32(vl, ph, o0, 0, 0, 0);
      vh = *(const bf16x8*)&smem[VF0 +
          ((((0 * 2 + wk) * 2 + 1) * 2 + t) * 64 + lane) * 8];
      vl = *(const bf16x8*)&smem[VF0 +
          ((((1 * 2 + wk) * 2 + 1) * 2 + t) * 64 + lane) * 8];
      o1 = MFMA32(vh, ph, o1, 0, 0, 0);
      o1 = MFMA32(vh, pl_, o1, 0, 0, 0);
      o1 = MFMA32(vl, ph, o1, 0, 0, 0);
    }
    __builtin_amdgcn_s_setprio(0);
    __syncthreads();
  }

  // ---- merge wk=0/1 (same wq) through LDS (overlays Kf/Vf, dead now)
  float* mL = (float*)(smem + KF0);  // 64
  float* lL = mL + 64;               // 64
  float* Om = lL + 64;               // [2][64][33]
  if (wk == 1) {
    if (lhi == 0) {
      mL[wq * 32 + l31] = m_run;
      lL[wq * 32 + l31] = l_run;
    }
#pragma unroll
    for (int mt = 0; mt < 2; ++mt)
#pragma unroll
      for (int r = 0; r < 16; ++r) {
        const int row = mt * 32 + (r & 3) + 8 * (r >> 2) + 4 * lhi;
        Om[(wq * 64 + row) * 33 + l31] = (mt ? o1[r] : o0[r]);
      }
  }
  __syncthreads();
  if (wk == 0) {
    const float m1 = mL[wq * 32 + l31];
    const float l1v = lL[wq * 32 + l31];
    const float mst = fmaxf(m_run, m1);
    const float a0 = __expf(m_run - mst), a1 = __expf(m1 - mst);
    const float inv = 1.f / (a0 * l_run + a1 * l1v);
    const int tok = b * 2048 + qg;
#pragma unroll
    for (int mt = 0; mt < 2; ++mt)
#pragma unroll
      for (int r = 0; r < 16; ++r) {
        const int row = mt * 32 + (r & 3) + 8 * (r >> 2) + 4 * lhi;
        const float val = (a0 * (mt ? o1[r] : o0[r]) +
                           a1 * Om[(wq * 64 + row) * 33 + l31]) *
                          inv;
        const int d = head * 64 + row;
        u16 hi, lo;
        split1(val, hi, lo);
        const size_t idx = ((size_t)(d >> 3) * 4096 + tok) * 8 + (d & 7);
        Othi[idx] = hi;
        Otlo[idx] = lo;
      }
  }
}

// ---------------------------------------------------------------------------
// GEMM2 (MFMA): out = o @ Wo^T + bo. EXACT R5/R7 reg-staged version.
// ---------------------------------------------------------------------------
#define G2_ISSUE(K0)                                        \
  {                                                         \
    g2ah = *(const uint4*)(srcAh + (size_t)(K0) * 4096);    \
    g2al = *(const uint4*)(srcAl + (size_t)(K0) * 4096);    \
    g2bh = *(const uint4*)(srcBh + (K0));                   \
    g2bl = *(const uint4*)(srcBl + (K0));                   \
  }
#define G2_COMMIT()                                         \
  {                                                         \
    *(uint4*)dAh = g2ah;                                    \
    *(uint4*)dAl = g2al;                                    \
    *(uint4*)dBh = g2bh;                                    \
    *(uint4*)dBl = g2bl;                                    \
  }

__global__ __launch_bounds__(256, 2) void gemm2_mfma(
    const u16* __restrict__ Othi, const u16* __restrict__ Otlo,
    const u16* __restrict__ Wohi, const u16* __restrict__ Wolo,
    const float* __restrict__ bo, float* __restrict__ out) {
  __shared__ __align__(16) u16 Af[2][2][2][64][8];  // 8 KB
  __shared__ __align__(16) u16 Bf[2][2][2][64][8];  // 8 KB
  const int tid = threadIdx.x;
  const int wave = tid >> 6, lane = tid & 63, l31 = lane & 31, lhi = lane >> 5;
  const int wm = wave >> 1, wn = wave & 1;
  const int m0 = blockIdx.y * 64, n0 = blockIdx.x * 64;

  const int cA = tid >> 6, tokA = tid & 63;
  u16* const dAh = &Af[0][tokA >> 5][cA >> 1][(cA & 1) * 32 + (tokA & 31)][0];
  u16* const dAl = &Af[1][tokA >> 5][cA >> 1][(cA & 1) * 32 + (tokA & 31)][0];
  const u16* const srcAh = Othi + ((size_t)cA * 4096 + m0 + tokA) * 8;
  const u16* const srcAl = Otlo + ((size_t)cA * 4096 + m0 + tokA) * 8;
  const int nB = tid >> 2, cB = tid & 3;
  u16* const dBh = &Bf[0][nB >> 5][cB >> 1][(cB & 1) * 32 + (nB & 31)][0];
  u16* const dBl = &Bf[1][nB >> 5][cB >> 1][(cB & 1) * 32 + (nB & 31)][0];
  const u16* const srcBh = Wohi + (size_t)(n0 + nB) * 512 + cB * 8;
  const u16* const srcBl = Wolo + (size_t)(n0 + nB) * 512 + cB * 8;

  f32x16 acc;
#pragma unroll
  for (int r = 0; r < 16; ++r) acc[r] = 0.f;

  uint4 g2ah, g2al, g2bh, g2bl;
  G2_ISSUE(0);
  for (int k0 = 0; k0 < 512; k0 += 32) {
    G2_COMMIT();
    __syncthreads();
    if (k0 < 480) G2_ISSUE(k0 + 32);
#pragma unroll
    for (int t = 0; t < 2; ++t) {
      const bf16x8 ah = *(const bf16x8*)&Af[0][wm][t][lane][0];
      const bf16x8 al = *(const bf16x8*)&Af[1][wm][t][lane][0];
      const bf16x8 bh = *(const bf16x8*)&Bf[0][wn][t][lane][0];
      const bf16x8 bl = *(const bf16x8*)&Bf[1][wn][t][lane][0];
      acc = MFMA32(ah, bh, acc, 0, 0, 0);
      acc = MFMA32(ah, bl, acc, 0, 0, 0);
      acc = MFMA32(al, bh, acc, 0, 0, 0);
    }
    __syncthreads();
  }

  const int n = n0 + wn * 32 + l31;
  const float bn = bo[n];
#pragma unroll
  for (int r = 0; r < 16; ++r) {
    const int m = m0 + wm * 32 + (r & 3) + 8 * (r >> 2) + 4 * lhi;
    out[(size_t)m * 512 + n] = acc[r] + bn;
  }
}

// ---------------------------------------------------------------------------
extern "C" void kernel_launch(void* const* d_in, const int* in_sizes, int n_in,
                              void* d_out, int out_size, void* d_ws,
                              size_t ws_size, hipStream_t stream) {
  const float* x = (const float*)d_in[0];
  const float* shift = (const float*)d_in[1];
  const float* mask = (const float*)d_in[2];
  const float* W = (const float*)d_in[3];
  const float* b = (const float*)d_in[4];
  const float* Wo = (const float*)d_in[5];
  const float* bo = (const float*)d_in[6];
  float* out = (float*)d_out;

  // ws (32 MiB): [0,6P) Q/K/V hi+lo planes (dead after attn; Wo planes reuse
  // the head of this region), [6P,8P) X planes (phase 1) then Ot planes.
  // W planes live in d_out until gemm2.
  const size_t P = (size_t)Hc * Bc * Sc * DHc;  // 2,097,152
  u16* ws0 = (u16*)d_ws;
  u16* Qhi = ws0;
  u16* Qlo = ws0 + P;
  u16* Khi = ws0 + 2 * P;
  u16* Klo = ws0 + 3 * P;
  u16* Vthi = ws0 + 4 * P;
  u16* Vtlo = ws0 + 5 * P;
  u16* Othi = ws0 + 6 * P;
  u16* Otlo = ws0 + 7 * P;
  u16* Xhi = ws0 + 6 * P;  // aliases Ot region (dead until attn)
  u16* Xlo = ws0 + 7 * P;
  u16* Whi = (u16*)out;  // d_out as scratch until gemm2
  u16* Wlo = (u16*)out + 786432;
  u16* Wohi = ws0;                // aliases Q region (dead after attn)
  u16* Wolo = ws0 + 262144;

  // 0) pre-split x and W to bf16 hi/lo planes
  presplit_xw<<<dim3(1408), 256, 0, stream>>>(x, W, Xhi, Xlo, Whi, Wlo);

  // 1) QKV projection (MFMA, copy staging from planes; Q pre-scaled)
  gemm1_mfma<<<dim3(NQKV / 64, (Bc * Sc) / 128), 256, 0, stream>>>(
      Xhi, Xlo, Whi, Wlo, b, Qhi, Qlo, Khi, Klo, Vthi, Vtlo);

  // 2) MFMA flash attention (R7 + [q][k] SM layout) -> Ot planes
  attn_mfma<<<dim3(Sc / 64, Bc, Hc), 256, 0, stream>>>(
      Qhi, Qlo, Khi, Klo, Vthi, Vtlo, shift, mask, Othi, Otlo);

  // 2b) pre-split Wo into the now-dead Q region
  presplit_wo<<<dim3(128), 256, 0, stream>>>(Wo, Wohi, Wolo);

  // 3) output projection (MFMA, reg-staged) -> out
  gemm2_mfma<<<dim3(Dc / 64, (Bc * Sc) / 64), 256, 0, stream>>>(
      Othi, Otlo, Wohi, Wolo, bo, out);
}